// Round 12
// baseline (1597.910 us; speedup 1.0000x reference)
//
#include <hip/hip_runtime.h>
#include <hip/hip_bf16.h>

#define N_NODES 50000
#define N_EDGES 800000
#define N_GRAPHS 128
#define NB2 391           // 128-node dst buckets
#define BCAP 4096         // edge capacity per bucket (λ≈2046, 45σ margin)
#define EPB 4096
#define PART_BLOCKS ((N_EDGES + EPB - 1) / EPB)  // 196

typedef __attribute__((ext_vector_type(8))) short short8;
typedef __attribute__((ext_vector_type(4))) float f32x4;

union B16x8 { uint4 u; short8 s; };

__device__ __forceinline__ unsigned bf16rn(float f) {
    unsigned u = __float_as_uint(f);
    return (u + 0x7FFFu + ((u >> 16) & 1u)) >> 16;
}
__device__ __forceinline__ unsigned packbf2(float a, float b) {
    return bf16rn(a) | (bf16rn(b) << 16);
}
__device__ __forceinline__ float2 unpkbf2(unsigned v) {
    return make_float2(__uint_as_float(v << 16), __uint_as_float(v & 0xFFFF0000u));
}

// ---------------- setup + partition (merged; fixed-capacity buckets, no scan) ----

__global__ __launch_bounds__(256) void setup_partition_kernel(
    const int* __restrict__ dst, const int* __restrict__ src, const float* __restrict__ w,
    int* __restrict__ cursor, int2* __restrict__ tmp, int E,
    const float* __restrict__ x, unsigned* __restrict__ xb,
    const float* __restrict__ W1, const float* __restrict__ W2,
    unsigned short* __restrict__ Wt, const int* __restrict__ gid,
    int* __restrict__ start, int n, int ngraphs) {
    __shared__ int lh[NB2];
    __shared__ int lbase[NB2];
    const int t = threadIdx.x;

    const int gtid = blockIdx.x * 256 + t;
    const int gsz = gridDim.x * 256;
    for (int i = gtid; i < n * 8; i += gsz) {
        float4 a = *(const float4*)(x + (size_t)i * 8);
        float4 b = *(const float4*)(x + (size_t)i * 8 + 4);
        uint4 o;
        o.x = packbf2(a.x, a.y);
        o.y = packbf2(a.z, a.w);
        o.z = packbf2(b.x, b.y);
        o.w = packbf2(b.z, b.w);
        *(uint4*)(xb + (size_t)i * 4) = o;
    }
    for (int i = gtid; i < 8 * 4096; i += gsz) {
        int mat = i >> 12, k = (i >> 6) & 63, nn = i & 63, l = mat >> 1;
        const float* Wsrc = (mat & 1) ? (W2 + l * 4096) : (W1 + l * 4096);
        Wt[(size_t)mat * 4096 + nn * 64 + k] = (unsigned short)bf16rn(Wsrc[k * 64 + nn]);
    }
    for (int i = gtid; i < n; i += gsz) {
        int g = gid[i];
        if (i == 0) {
            for (int q = 0; q <= g; ++q) start[q] = 0;
        } else {
            int p = gid[i - 1];
            if (p != g)
                for (int q = p + 1; q <= g; ++q) start[q] = i;
        }
        if (i == n - 1)
            for (int q = g + 1; q <= ngraphs; ++q) start[q] = n;
    }

    for (int i = t; i < NB2; i += 256) lh[i] = 0;
    __syncthreads();
    int base = blockIdx.x * EPB;
    int d[EPB / 256];
#pragma unroll
    for (int i = 0; i < EPB / 256; ++i) {
        int e = base + i * 256 + t;
        d[i] = (e < E) ? dst[e] : -1;
        if (d[i] >= 0) atomicAdd(&lh[d[i] >> 7], 1);
    }
    __syncthreads();
    for (int i = t; i < NB2; i += 256) {
        int v = lh[i];
        if (v) lbase[i] = atomicAdd(&cursor[i], v);
        lh[i] = 0;
    }
    __syncthreads();
#pragma unroll
    for (int i = 0; i < EPB / 256; ++i) {
        int e = base + i * 256 + t;
        if (d[i] >= 0) {
            int b = d[i] >> 7;
            int dl = d[i] & 127;
            int rank = atomicAdd(&lh[b], 1);
            tmp[(size_t)b * BCAP + lbase[b] + rank] =
                make_int2(src[e] | (dl << 16), __float_as_int(w[e]));
        }
    }
}

// ---------------- fused layer kernel: LDS-scatter agg + gemm1 (+pool blocks) -------------

__global__ __launch_bounds__(512) void layer1_kernel(
    const unsigned* __restrict__ hb, const int2* __restrict__ tmp,
    const int* __restrict__ ecnt, const float* __restrict__ eps, int layer,
    const unsigned short* __restrict__ Wt1, const float* __restrict__ b1,
    unsigned short* __restrict__ T, float* __restrict__ stats1,
    const float* __restrict__ tstats, const float* __restrict__ tg,
    const float* __restrict__ tb, int transform,
    const int* __restrict__ start, const float* __restrict__ pW,
    const float* __restrict__ pb, float* __restrict__ score, int n) {
    __shared__ float accum[128 * 65];  // 33.3 KB; reused as cstage (bf16) in epilogue
    __shared__ float rsum[64 * 33];
    __shared__ float rsq[64 * 33];
    __shared__ float sc[64], sh[64];
    const int t = threadIdx.x;

    if (transform && t < 64) {
        float inv_n = 1.0f / (float)n;
        float mean = tstats[t] * inv_n;
        float var = tstats[64 + t] * inv_n - mean * mean;
        float s = tg[t] * rsqrtf(var + 1e-5f);
        sc[t] = s;
        sh[t] = tb[t] - mean * s;
    }
    __syncthreads();

    if ((int)blockIdx.x >= NB2) {
        // ---- pool role (512 threads: 32 row-groups x 16 lanes) ----
        float(*red)[68] = (float(*)[68])accum;  // 32x68
        float* pl = accum + 32 * 68;
        const int g = blockIdx.x - NB2;
        const int r32 = t >> 4;
        const int qq = t & 15;
        const int k0 = qq << 2;
        int i0 = start[g], i1 = start[g + 1];
        float4 ps = make_float4(0.f, 0.f, 0.f, 0.f);
        for (int i = i0 + r32; i < i1; i += 32) {
            uint2 u = *(const uint2*)(hb + (size_t)i * 32 + qq * 2);
            float2 a = unpkbf2(u.x), b = unpkbf2(u.y);
            if (transform) {
                a.x = fmaxf(fmaf(a.x, sc[k0 + 0], sh[k0 + 0]), 0.f);
                a.y = fmaxf(fmaf(a.y, sc[k0 + 1], sh[k0 + 1]), 0.f);
                b.x = fmaxf(fmaf(b.x, sc[k0 + 2], sh[k0 + 2]), 0.f);
                b.y = fmaxf(fmaf(b.y, sc[k0 + 3], sh[k0 + 3]), 0.f);
            }
            ps.x += a.x; ps.y += a.y; ps.z += b.x; ps.w += b.y;
        }
        red[r32][k0 + 0] = ps.x;
        red[r32][k0 + 1] = ps.y;
        red[r32][k0 + 2] = ps.z;
        red[r32][k0 + 3] = ps.w;
        __syncthreads();
        if (t < 64) {
            float s = 0.f;
#pragma unroll
            for (int r = 0; r < 32; ++r) s += red[r][t];
            pl[t] = s;
        }
        __syncthreads();
        if (t < 16) {
            float s = pb[t];
#pragma unroll 8
            for (int d = 0; d < 64; ++d) s += pl[d] * pW[d * 16 + t];
            score[g * 16 + t] = transform ? (score[g * 16 + t] + s) : s;
        }
        return;
    }

    const int nb = blockIdx.x;
    const int node0 = nb * 128;
    const float e1 = 1.0f + eps[layer];

    // ---- init accum with (1+eps) * transform(h[node]) ----
    {
        const int grp = t >> 4;   // 0..31
        const int li = t & 15;
        for (int rr = grp; rr < 128; rr += 32) {
            int node = node0 + rr;
            float4 v = make_float4(0.f, 0.f, 0.f, 0.f);
            if (node < n) {
                uint2 u = *(const uint2*)(hb + (size_t)node * 32 + li * 2);
                float2 a = unpkbf2(u.x), b = unpkbf2(u.y);
                if (transform) {
                    a.x = fmaxf(fmaf(a.x, sc[li * 4 + 0], sh[li * 4 + 0]), 0.f);
                    a.y = fmaxf(fmaf(a.y, sc[li * 4 + 1], sh[li * 4 + 1]), 0.f);
                    b.x = fmaxf(fmaf(b.x, sc[li * 4 + 2], sh[li * 4 + 2]), 0.f);
                    b.y = fmaxf(fmaf(b.y, sc[li * 4 + 3], sh[li * 4 + 3]), 0.f);
                }
                v = make_float4(e1 * a.x, e1 * a.y, e1 * b.x, e1 * b.y);
            }
            accum[rr * 65 + li * 4 + 0] = v.x;
            accum[rr * 65 + li * 4 + 1] = v.y;
            accum[rr * 65 + li * 4 + 2] = v.z;
            accum[rr * 65 + li * 4 + 3] = v.w;
        }
    }
    __syncthreads();

    // ---- stream edges: one full wave per edge, lane = feature, 8 edges in flight ----
    {
        const int wv = t >> 6;  // 0..7
        const int f = t & 63;
        const float scf = transform ? sc[f] : 1.f;
        const float shf = transform ? sh[f] : 0.f;
        const unsigned short* hs = (const unsigned short*)hb;
        int cnt = ecnt[nb];
        if (cnt > BCAP) cnt = BCAP;
        const int2* tb2 = tmp + (size_t)nb * BCAP;
        for (int base = wv * 8; base < cnt; base += 64) {
            int sdl[8];
            float wgt[8];
#pragma unroll
            for (int u = 0; u < 8; ++u) {
                int e = base + u;
                bool valid = e < cnt;
                int2 p = tb2[valid ? e : 0];
                sdl[u] = p.x;
                wgt[u] = valid ? __int_as_float(p.y) : 0.f;
            }
            unsigned hv[8];
#pragma unroll
            for (int u = 0; u < 8; ++u)
                hv[u] = hs[(size_t)(sdl[u] & 0xFFFF) * 64 + f];
#pragma unroll
            for (int u = 0; u < 8; ++u) {
                float val = __uint_as_float(hv[u] << 16);
                if (transform) val = fmaxf(fmaf(val, scf, shf), 0.f);  // FIX: guard BN+ReLU
                val *= wgt[u];
                atomicAdd(&accum[((sdl[u] >> 16) & 127) * 65 + f], val);
            }
        }
    }
    __syncthreads();

    // ---- MFMA gemm1 from LDS accum ----
    const int wv = t >> 6;
    const int lane = t & 63;
    const int m = lane & 15;
    const int q = lane >> 4;

    B16x8 bf[4][2];
#pragma unroll
    for (int tc = 0; tc < 4; ++tc)
#pragma unroll
        for (int kc = 0; kc < 2; ++kc)
            bf[tc][kc].u = *(const uint4*)(Wt1 + (size_t)(tc * 16 + m) * 64 + kc * 32 + q * 8);

    B16x8 af[2];
    {
        int r = wv * 16 + m;
#pragma unroll
        for (int kc = 0; kc < 2; ++kc) {
            const float* row = accum + r * 65 + kc * 32 + q * 8;
            uint4 uu;
            uu.x = packbf2(row[0], row[1]);
            uu.y = packbf2(row[2], row[3]);
            uu.z = packbf2(row[4], row[5]);
            uu.w = packbf2(row[6], row[7]);
            af[kc].u = uu;
        }
    }
    __syncthreads();  // all frag loads done before cstage clobbers accum

    f32x4 acc4[4];
#pragma unroll
    for (int tc = 0; tc < 4; ++tc) {
        acc4[tc] = (f32x4){0.f, 0.f, 0.f, 0.f};
        acc4[tc] = __builtin_amdgcn_mfma_f32_16x16x32_bf16(af[0].s, bf[tc][0].s, acc4[tc], 0, 0, 0);
        acc4[tc] = __builtin_amdgcn_mfma_f32_16x16x32_bf16(af[1].s, bf[tc][1].s, acc4[tc], 0, 0, 0);
    }

    float bc[4];
#pragma unroll
    for (int tc = 0; tc < 4; ++tc) bc[tc] = b1[tc * 16 + m];

    unsigned short* cstage = (unsigned short*)accum;
    float psum[4] = {0, 0, 0, 0}, psq[4] = {0, 0, 0, 0};
#pragma unroll
    for (int reg = 0; reg < 4; ++reg) {
        int r = wv * 16 + q * 4 + reg;
        int gr = node0 + r;
        bool ok = gr < n;
#pragma unroll
        for (int tc = 0; tc < 4; ++tc) {
            float val = acc4[tc][reg] + bc[tc];
            int c = tc * 16 + m;
            cstage[r * 64 + ((((c >> 3) ^ (r & 7)) << 3) | (c & 7))] =
                (unsigned short)bf16rn(ok ? val : 0.f);
            if (ok) {
                psum[tc] += val;
                psq[tc] += val * val;
            }
        }
    }

    // coalesced T store (wave-private rows; no barrier needed)
#pragma unroll
    for (int rep = 0; rep < 2; ++rep) {
        int idx = rep * 64 + lane;
        int rl = idx >> 3, k = idx & 7;
        int r = wv * 16 + rl;
        int gr = node0 + r;
        if (gr < n) {
            uint4 v = *(const uint4*)(cstage + r * 64 + ((k ^ (r & 7)) << 3));
            *(uint4*)(T + (size_t)gr * 64 + k * 8) = v;
        }
    }

    int contrib = wv * 4 + q;  // 0..31
#pragma unroll
    for (int tc = 0; tc < 4; ++tc) {
        int c = tc * 16 + m;
        rsum[c * 33 + contrib] = psum[tc];
        rsq[c * 33 + contrib] = psq[tc];
    }
    __syncthreads();
    if (t < 64) {
        float s = 0.f, q2 = 0.f;
#pragma unroll
        for (int i = 0; i < 32; ++i) {
            s += rsum[t * 33 + i];
            q2 += rsq[t * 33 + i];
        }
        atomicAdd(&stats1[t], s);
        atomicAdd(&stats1[64 + t], q2);
    }
}

// ---------------- stage2: bf16 MFMA GEMM (R10) ----------

#define GTILE 128

__global__ __launch_bounds__(256) void mfma_gemm(const unsigned short* __restrict__ A,
                                                 const unsigned short* __restrict__ Wt,
                                                 const float* __restrict__ bias,
                                                 unsigned short* __restrict__ out,
                                                 float* __restrict__ stats_out,
                                                 const float* __restrict__ stats_in,
                                                 const float* __restrict__ gamma,
                                                 const float* __restrict__ beta,
                                                 int n, int transform) {
    __shared__ float sc[64], sh[64];
    __shared__ unsigned short cstage[GTILE * 64];
    __shared__ float rsum[64 * 17];
    __shared__ float rsq[64 * 17];

    const int t = threadIdx.x;
    if (transform && t < 64) {
        float inv_n = 1.0f / (float)n;
        float mean = stats_in[t] * inv_n;
        float var = stats_in[64 + t] * inv_n - mean * mean;
        float s = gamma[t] * rsqrtf(var + 1e-5f);
        sc[t] = s;
        sh[t] = beta[t] - mean * s;
    }
    __syncthreads();

    const int wid = t >> 6;
    const int lane = t & 63;
    const int m = lane & 15;
    const int q = lane >> 4;
    const int rowbase = blockIdx.x * GTILE + wid * 32;

    B16x8 bf[4][2];
#pragma unroll
    for (int tc = 0; tc < 4; ++tc)
#pragma unroll
        for (int kc = 0; kc < 2; ++kc)
            bf[tc][kc].u = *(const uint4*)(Wt + (size_t)(tc * 16 + m) * 64 + kc * 32 + q * 8);

    B16x8 af[2][2];
#pragma unroll
    for (int tr = 0; tr < 2; ++tr) {
        int gr = rowbase + tr * 16 + m;
#pragma unroll
        for (int kc = 0; kc < 2; ++kc) {
            if (gr < n)
                af[tr][kc].u = *(const uint4*)(A + (size_t)gr * 64 + kc * 32 + q * 8);
            else
                af[tr][kc].u = make_uint4(0, 0, 0, 0);
        }
    }

    if (transform) {
        int k0base = q * 8;
#pragma unroll
        for (int tr = 0; tr < 2; ++tr)
#pragma unroll
            for (int kc = 0; kc < 2; ++kc) {
                int k0 = kc * 32 + k0base;
                float4 s0 = *(const float4*)(sc + k0);
                float4 s1 = *(const float4*)(sc + k0 + 4);
                float4 h0 = *(const float4*)(sh + k0);
                float4 h1 = *(const float4*)(sh + k0 + 4);
                uint4 uu = af[tr][kc].u;
                float2 p0 = unpkbf2(uu.x), p1 = unpkbf2(uu.y);
                float2 p2 = unpkbf2(uu.z), p3 = unpkbf2(uu.w);
                p0.x = fmaxf(fmaf(p0.x, s0.x, h0.x), 0.f);
                p0.y = fmaxf(fmaf(p0.y, s0.y, h0.y), 0.f);
                p1.x = fmaxf(fmaf(p1.x, s0.z, h0.z), 0.f);
                p1.y = fmaxf(fmaf(p1.y, s0.w, h0.w), 0.f);
                p2.x = fmaxf(fmaf(p2.x, s1.x, h1.x), 0.f);
                p2.y = fmaxf(fmaf(p2.y, s1.y, h1.y), 0.f);
                p3.x = fmaxf(fmaf(p3.x, s1.z, h1.z), 0.f);
                p3.y = fmaxf(fmaf(p3.y, s1.w, h1.w), 0.f);
                uu.x = packbf2(p0.x, p0.y);
                uu.y = packbf2(p1.x, p1.y);
                uu.z = packbf2(p2.x, p2.y);
                uu.w = packbf2(p3.x, p3.y);
                af[tr][kc].u = uu;
            }
    }

    f32x4 acc[2][4];
#pragma unroll
    for (int tr = 0; tr < 2; ++tr)
#pragma unroll
        for (int tc = 0; tc < 4; ++tc) {
            acc[tr][tc] = (f32x4){0.f, 0.f, 0.f, 0.f};
            acc[tr][tc] = __builtin_amdgcn_mfma_f32_16x16x32_bf16(af[tr][0].s, bf[tc][0].s,
                                                                  acc[tr][tc], 0, 0, 0);
            acc[tr][tc] = __builtin_amdgcn_mfma_f32_16x16x32_bf16(af[tr][1].s, bf[tc][1].s,
                                                                  acc[tr][tc], 0, 0, 0);
        }

    float bc[4];
#pragma unroll
    for (int tc = 0; tc < 4; ++tc) bc[tc] = bias[tc * 16 + m];

    float psum[4] = {0, 0, 0, 0}, psq[4] = {0, 0, 0, 0};
#pragma unroll
    for (int tr = 0; tr < 2; ++tr)
#pragma unroll
        for (int reg = 0; reg < 4; ++reg) {
            int rl = wid * 32 + tr * 16 + q * 4 + reg;
            int gr = blockIdx.x * GTILE + rl;
            int sw = ((rl >> 2) & 3) << 4;
            bool ok = gr < n;
#pragma unroll
            for (int tc = 0; tc < 4; ++tc) {
                float val = acc[tr][tc][reg] + bc[tc];
                int col = tc * 16 + m;
                cstage[rl * 64 + (col ^ sw)] = (unsigned short)bf16rn(ok ? val : 0.f);
                if (ok) {
                    psum[tc] += val;
                    psq[tc] += val * val;
                }
            }
        }

    int contrib = wid * 4 + q;
#pragma unroll
    for (int tc = 0; tc < 4; ++tc) {
        int c = tc * 16 + m;
        rsum[c * 17 + contrib] = psum[tc];
        rsq[c * 17 + contrib] = psq[tc];
    }
    __syncthreads();

#pragma unroll
    for (int rep = 0; rep < 4; ++rep) {
        int idx = rep * 256 + t;
        int rl = idx >> 3;
        int k = idx & 7;
        int gr = blockIdx.x * GTILE + rl;
        if (gr < n) {
            int klds = k ^ (((rl >> 2) & 3) << 1);
            uint4 v = *(const uint4*)(cstage + rl * 64 + klds * 8);
            *(uint4*)(out + (size_t)gr * 64 + k * 8) = v;
        }
    }

    if (t < 64) {
        float s = 0.f, qq = 0.f;
#pragma unroll
        for (int i = 0; i < 16; ++i) {
            s += rsum[t * 17 + i];
            qq += rsq[t * 17 + i];
        }
        atomicAdd(&stats_out[t], s);
        atomicAdd(&stats_out[64 + t], qq);
    }
}

// ---------------- standalone pool+score (final layer only) ----------------

__global__ __launch_bounds__(256) void pool_score_kernel(const unsigned* __restrict__ hb,
                                                         const int* __restrict__ start,
                                                         const float* __restrict__ pW,
                                                         const float* __restrict__ pb,
                                                         float* __restrict__ score,
                                                         const float* __restrict__ stats,
                                                         const float* __restrict__ gamma,
                                                         const float* __restrict__ beta,
                                                         int n, int mode) {
    __shared__ float red[16][68];
    __shared__ float sc[64], sh[64], pl[64];
    const int t = threadIdx.x;
    const int g = blockIdx.x;
    if (mode && t < 64) {
        float inv_n = 1.0f / (float)n;
        float mean = stats[t] * inv_n;
        float var = stats[64 + t] * inv_n - mean * mean;
        float s = gamma[t] * rsqrtf(var + 1e-5f);
        sc[t] = s;
        sh[t] = beta[t] - mean * s;
    }
    __syncthreads();

    const int r16 = t >> 4;
    const int qq = t & 15;
    const int k0 = qq << 2;
    int i0 = start[g], i1 = start[g + 1];
    float4 ps = make_float4(0.f, 0.f, 0.f, 0.f);
    for (int i = i0 + r16; i < i1; i += 16) {
        uint2 u = *(const uint2*)(hb + (size_t)i * 32 + qq * 2);
        float2 a = unpkbf2(u.x);
        float2 b = unpkbf2(u.y);
        if (mode) {
            a.x = fmaxf(fmaf(a.x, sc[k0 + 0], sh[k0 + 0]), 0.f);
            a.y = fmaxf(fmaf(a.y, sc[k0 + 1], sh[k0 + 1]), 0.f);
            b.x = fmaxf(fmaf(b.x, sc[k0 + 2], sh[k0 + 2]), 0.f);
            b.y = fmaxf(fmaf(b.y, sc[k0 + 3], sh[k0 + 3]), 0.f);
        }
        ps.x += a.x; ps.y += a.y; ps.z += b.x; ps.w += b.y;
    }
    red[r16][k0 + 0] = ps.x;
    red[r16][k0 + 1] = ps.y;
    red[r16][k0 + 2] = ps.z;
    red[r16][k0 + 3] = ps.w;
    __syncthreads();
    if (t < 64) {
        float s = 0.f;
#pragma unroll
        for (int r = 0; r < 16; ++r) s += red[r][t];
        pl[t] = s;
    }
    __syncthreads();
    if (t < 16) {
        float s = pb[t];
#pragma unroll 8
        for (int d = 0; d < 64; ++d) s += pl[d] * pW[d * 16 + t];
        score[g * 16 + t] = mode ? (score[g * 16 + t] + s) : s;
    }
}

// ---------------- host ----------------

extern "C" void kernel_launch(void* const* d_in, const int* in_sizes, int n_in,
                              void* d_out, int out_size, void* d_ws, size_t ws_size,
                              hipStream_t stream) {
    const float* x = (const float*)d_in[0];
    const float* w = (const float*)d_in[1];
    const int* src = (const int*)d_in[2];
    const int* dst = (const int*)d_in[3];
    const int* gid = (const int*)d_in[4];
    const float* eps = (const float*)d_in[5];
    const float* W1 = (const float*)d_in[6];
    const float* b1 = (const float*)d_in[7];
    const float* bng = (const float*)d_in[8];
    const float* bnb = (const float*)d_in[9];
    const float* W2 = (const float*)d_in[10];
    const float* b2 = (const float*)d_in[11];
    const float* og = (const float*)d_in[12];
    const float* ob = (const float*)d_in[13];
    const float* pW = (const float*)d_in[14];
    const float* pb = (const float*)d_in[15];
    float* out = (float*)d_out;

    const int N = N_NODES, E = N_EDGES, G = N_GRAPHS;

    unsigned* base = (unsigned*)d_ws;
    unsigned* xb = base;                       // N*32 (buffer 0)
    unsigned* HA = xb + (size_t)N * 32;        // N*32 (buffer 1)
    unsigned* HB = HA + (size_t)N * 32;        // N*32 (buffer 2)
    float* stats = (float*)(HB + (size_t)N * 32);  // 1024 (zeroed)
    int* cursor = (int*)(stats + 1024);        // NB2 (zeroed)
    int* start = cursor + NB2 + 1;             // G+1 (pad 132)
    unsigned short* Wt = (unsigned short*)(start + 132);  // 8*4096
    int2* tmp = (int2*)(Wt + 8 * 4096);        // NB2*BCAP int2 = 12.8 MB

    hipMemsetAsync(stats, 0, (size_t)(1024 + NB2) * sizeof(float), stream);

    hipLaunchKernelGGL(setup_partition_kernel, dim3(PART_BLOCKS), dim3(256), 0, stream, dst, src,
                       w, cursor, tmp, E, x, xb, W1, W2, Wt, gid, start, N, G);

    unsigned* cur = xb;
    unsigned* Tbuf = HA;
    unsigned* next = HB;
    const int gemm_blocks = (N + GTILE - 1) / GTILE;
    for (int l = 0; l < 4; ++l) {
        const float* tr_stats = (l == 0) ? nullptr : stats + (l - 1) * 256 + 128;
        const float* tr_g = (l == 0) ? nullptr : og + (l - 1) * 64;
        const float* tr_b = (l == 0) ? nullptr : ob + (l - 1) * 64;
        // fused agg+gemm1 (cur -> Tbuf, stats1) + pool of cur -> score
        hipLaunchKernelGGL(layer1_kernel, dim3(NB2 + G), dim3(512), 0, stream, cur, tmp, cursor,
                           eps, l, Wt + (size_t)(l * 2) * 4096, b1 + l * 64,
                           (unsigned short*)Tbuf, stats + l * 256, tr_stats, tr_g, tr_b,
                           l == 0 ? 0 : 1, start, pW + (size_t)l * 1024, pb + l * 16, out, N);
        // gemm2: Tbuf -> next (BN(stats1)+ReLU fused on read), stats2
        hipLaunchKernelGGL(mfma_gemm, dim3(gemm_blocks), dim3(256), 0, stream,
                           (const unsigned short*)Tbuf, Wt + (size_t)(l * 2 + 1) * 4096,
                           b2 + l * 64, (unsigned short*)next, stats + l * 256 + 128,
                           stats + l * 256, bng + l * 64, bnb + l * 64, N, 1);
        unsigned* old_cur = cur;
        unsigned* old_T = Tbuf;
        cur = next;
        Tbuf = old_cur;
        next = old_T;
    }
    // final pool of h_3 with layer-3 outer BN
    hipLaunchKernelGGL(pool_score_kernel, dim3(G), dim3(256), 0, stream, cur, start,
                       pW + 4 * 1024, pb + 4 * 16, out, stats + 3 * 256 + 128, og + 3 * 64,
                       ob + 3 * 64, N, 1);
}

// Round 13
// 387.575 us; speedup vs baseline: 4.1228x; 4.1228x over previous
//
#include <hip/hip_runtime.h>
#include <hip/hip_bf16.h>

#define N_NODES 50000
#define N_EDGES 800000
#define N_GRAPHS 128
#define NB2 391           // 128-node dst buckets
#define BCAP 4096         // bucket capacity (lambda~2046, 45 sigma margin; validated R12)
#define EPB 4096
#define PART_BLOCKS ((N_EDGES + EPB - 1) / EPB)  // 196

typedef __attribute__((ext_vector_type(8))) short short8;
typedef __attribute__((ext_vector_type(4))) float f32x4;

union B16x8 { uint4 u; short8 s; };

__device__ __forceinline__ unsigned bf16rn(float f) {
    unsigned u = __float_as_uint(f);
    return (u + 0x7FFFu + ((u >> 16) & 1u)) >> 16;
}
__device__ __forceinline__ unsigned packbf2(float a, float b) {
    return bf16rn(a) | (bf16rn(b) << 16);
}
__device__ __forceinline__ float2 unpkbf2(unsigned v) {
    return make_float2(__uint_as_float(v << 16), __uint_as_float(v & 0xFFFF0000u));
}

// ---------------- setup + partition (1 dispatch; fixed-capacity buckets, R12-validated) ----

__global__ __launch_bounds__(256) void setup_partition_kernel(
    const int* __restrict__ dst, const int* __restrict__ src, const float* __restrict__ w,
    int* __restrict__ cursor, int2* __restrict__ tmp, int E,
    const float* __restrict__ x, unsigned* __restrict__ xb,
    const float* __restrict__ W1, const float* __restrict__ W2,
    unsigned short* __restrict__ Wt, const int* __restrict__ gid,
    int* __restrict__ start, int n, int ngraphs) {
    __shared__ int lh[NB2];
    __shared__ int lbase[NB2];
    const int t = threadIdx.x;

    const int gtid = blockIdx.x * 256 + t;
    const int gsz = gridDim.x * 256;
    for (int i = gtid; i < n * 8; i += gsz) {
        float4 a = *(const float4*)(x + (size_t)i * 8);
        float4 b = *(const float4*)(x + (size_t)i * 8 + 4);
        uint4 o;
        o.x = packbf2(a.x, a.y);
        o.y = packbf2(a.z, a.w);
        o.z = packbf2(b.x, b.y);
        o.w = packbf2(b.z, b.w);
        *(uint4*)(xb + (size_t)i * 4) = o;
    }
    for (int i = gtid; i < 8 * 4096; i += gsz) {
        int mat = i >> 12, k = (i >> 6) & 63, nn = i & 63, l = mat >> 1;
        const float* Wsrc = (mat & 1) ? (W2 + l * 4096) : (W1 + l * 4096);
        Wt[(size_t)mat * 4096 + nn * 64 + k] = (unsigned short)bf16rn(Wsrc[k * 64 + nn]);
    }
    for (int i = gtid; i < n; i += gsz) {
        int g = gid[i];
        if (i == 0) {
            for (int q = 0; q <= g; ++q) start[q] = 0;
        } else {
            int p = gid[i - 1];
            if (p != g)
                for (int q = p + 1; q <= g; ++q) start[q] = i;
        }
        if (i == n - 1)
            for (int q = g + 1; q <= ngraphs; ++q) start[q] = n;
    }

    for (int i = t; i < NB2; i += 256) lh[i] = 0;
    __syncthreads();
    int base = blockIdx.x * EPB;
    int d[EPB / 256];
#pragma unroll
    for (int i = 0; i < EPB / 256; ++i) {
        int e = base + i * 256 + t;
        d[i] = (e < E) ? dst[e] : -1;
        if (d[i] >= 0) atomicAdd(&lh[d[i] >> 7], 1);
    }
    __syncthreads();
    for (int i = t; i < NB2; i += 256) {
        int v = lh[i];
        if (v) lbase[i] = atomicAdd(&cursor[i], v);
        lh[i] = 0;
    }
    __syncthreads();
#pragma unroll
    for (int i = 0; i < EPB / 256; ++i) {
        int e = base + i * 256 + t;
        if (d[i] >= 0) {
            int b = d[i] >> 7;
            int dl = d[i] & 127;
            int rank = atomicAdd(&lh[b], 1);
            tmp[(size_t)b * BCAP + lbase[b] + rank] =
                make_int2(src[e] | (dl << 16), __float_as_int(w[e]));
        }
    }
}

// ---------------- node sort: 1 block per bucket -> bucket-major pack + per-node (start,end) --

__global__ __launch_bounds__(256) void node_sort_kernel(const int2* __restrict__ tmp,
                                                        const int* __restrict__ ecnt,
                                                        int2* __restrict__ row_se,
                                                        unsigned* __restrict__ pack, int n) {
    __shared__ int hist[128];
    __shared__ int run[128];
    __shared__ int s[256];
    const int t = threadIdx.x;
    const int b = blockIdx.x;
    int cnt = ecnt[b];
    if (cnt > BCAP) cnt = BCAP;
    const int2* tb2 = tmp + (size_t)b * BCAP;
    const int gbase = b * BCAP;

    if (t < 128) hist[t] = 0;
    __syncthreads();
    for (int j = t; j < cnt; j += 256) atomicAdd(&hist[(tb2[j].x >> 16) & 127], 1);
    __syncthreads();
    int v = (t < 128) ? hist[t] : 0;
    s[t] = v;
    __syncthreads();
    for (int off = 1; off < 128; off <<= 1) {
        int u = (t >= off) ? s[t - off] : 0;
        __syncthreads();
        s[t] += u;
        __syncthreads();
    }
    if (t < 128) {
        int excl = s[t] - v;
        int node = b * 128 + t;
        if (node < n) row_se[node] = make_int2(gbase + excl, gbase + excl + v);
        run[t] = gbase + excl;
    }
    __syncthreads();
    for (int j = t; j < cnt; j += 256) {
        int2 p = tb2[j];
        int pos = atomicAdd(&run[(p.x >> 16) & 127], 1);
        pack[pos] = (unsigned)(p.x & 0xFFFF) | (bf16rn(__int_as_float(p.y)) << 16);
    }
}

// ---------------- agg (+prev outer BN on the fly) + fused pool of same input (R10) --------

__global__ __launch_bounds__(256) void agg_kernel(const unsigned* __restrict__ hb,
                                                  const unsigned* __restrict__ pack,
                                                  const int2* __restrict__ row_se,
                                                  const float* __restrict__ eps, int layer,
                                                  unsigned* __restrict__ outb, int n,
                                                  const float* __restrict__ stats,
                                                  const float* __restrict__ gamma,
                                                  const float* __restrict__ beta,
                                                  int transform, int agg_blocks,
                                                  const int* __restrict__ start,
                                                  const float* __restrict__ pW,
                                                  const float* __restrict__ pb,
                                                  float* __restrict__ score) {
    __shared__ float sc[64], sh[64];
    const int t = threadIdx.x;
    if (transform) {
        if (t < 64) {
            float inv_n = 1.0f / (float)n;
            float mean = stats[t] * inv_n;
            float var = stats[64 + t] * inv_n - mean * mean;
            float s = gamma[t] * rsqrtf(var + 1e-5f);
            sc[t] = s;
            sh[t] = beta[t] - mean * s;
        }
        __syncthreads();
    }

    if ((int)blockIdx.x >= agg_blocks) {
        // ---- pool role ----
        __shared__ float red[16][68];
        __shared__ float pl[64];
        const int g = blockIdx.x - agg_blocks;
        const int r16 = t >> 4;
        const int qq = t & 15;
        const int k0 = qq << 2;
        int i0 = start[g], i1 = start[g + 1];
        float4 ps = make_float4(0.f, 0.f, 0.f, 0.f);
        for (int i = i0 + r16; i < i1; i += 16) {
            uint2 u = *(const uint2*)(hb + (size_t)i * 32 + qq * 2);
            float2 a = unpkbf2(u.x);
            float2 b = unpkbf2(u.y);
            if (transform) {
                a.x = fmaxf(fmaf(a.x, sc[k0 + 0], sh[k0 + 0]), 0.f);
                a.y = fmaxf(fmaf(a.y, sc[k0 + 1], sh[k0 + 1]), 0.f);
                b.x = fmaxf(fmaf(b.x, sc[k0 + 2], sh[k0 + 2]), 0.f);
                b.y = fmaxf(fmaf(b.y, sc[k0 + 3], sh[k0 + 3]), 0.f);
            }
            ps.x += a.x; ps.y += a.y; ps.z += b.x; ps.w += b.y;
        }
        red[r16][k0 + 0] = ps.x;
        red[r16][k0 + 1] = ps.y;
        red[r16][k0 + 2] = ps.z;
        red[r16][k0 + 3] = ps.w;
        __syncthreads();
        if (t < 64) {
            float s = 0.f;
#pragma unroll
            for (int r = 0; r < 16; ++r) s += red[r][t];
            pl[t] = s;
        }
        __syncthreads();
        if (t < 16) {
            float s = pb[t];
#pragma unroll 8
            for (int d = 0; d < 64; ++d) s += pl[d] * pW[d * 16 + t];
            score[g * 16 + t] = transform ? (score[g * 16 + t] + s) : s;
        }
        return;
    }

    // ---- agg role: 1 wave per node, 16 gathers in flight ----
    int node = blockIdx.x * 4 + (t >> 6);
    if (node >= n) return;
    const int lane = t & 63;
    const int slot = lane >> 4;
    const int li = lane & 15;

    float4 sc4 = make_float4(1.f, 1.f, 1.f, 1.f);
    float4 sh4 = make_float4(0.f, 0.f, 0.f, 0.f);
    if (transform) {
        sc4 = *(const float4*)(sc + li * 4);
        sh4 = *(const float4*)(sh + li * 4);
    }
    float e1 = 1.0f + eps[layer];

    float4 acc = make_float4(0.f, 0.f, 0.f, 0.f);
    {
        uint2 su = *(const uint2*)(hb + (size_t)node * 32 + li * 2);
        if (slot == 0) {
            float2 a = unpkbf2(su.x), b = unpkbf2(su.y);
            if (transform) {
                a.x = fmaxf(fmaf(a.x, sc4.x, sh4.x), 0.f);
                a.y = fmaxf(fmaf(a.y, sc4.y, sh4.y), 0.f);
                b.x = fmaxf(fmaf(b.x, sc4.z, sh4.z), 0.f);
                b.y = fmaxf(fmaf(b.y, sc4.w, sh4.w), 0.f);
            }
            acc.x = e1 * a.x; acc.y = e1 * a.y; acc.z = e1 * b.x; acc.w = e1 * b.y;
        }
    }

    int2 se = row_se[node];
    int j0 = se.x, j1 = se.y;
    int j = j0;
    unsigned pk[4];
    if (j < j1) {
#pragma unroll
        for (int u = 0; u < 4; ++u) {
            int idx = j + slot + u * 4;
            pk[u] = pack[idx < j1 ? idx : j1 - 1];
        }
    }
    while (j < j1) {
        float wv[4];
        uint2 g[4];
#pragma unroll
        for (int u = 0; u < 4; ++u) {
            int jj = j + slot + u * 4;
            wv[u] = (jj < j1) ? __uint_as_float(pk[u] & 0xFFFF0000u) : 0.f;
        }
#pragma unroll
        for (int u = 0; u < 4; ++u)
            g[u] = *(const uint2*)(hb + (size_t)(pk[u] & 0xFFFFu) * 32 + li * 2);
        j += 16;
        if (j < j1) {
#pragma unroll
            for (int u = 0; u < 4; ++u) {
                int idx = j + slot + u * 4;
                pk[u] = pack[idx < j1 ? idx : j1 - 1];
            }
        }
#pragma unroll
        for (int u = 0; u < 4; ++u) {
            float2 a = unpkbf2(g[u].x), b = unpkbf2(g[u].y);
            if (transform) {
                a.x = fmaxf(fmaf(a.x, sc4.x, sh4.x), 0.f);
                a.y = fmaxf(fmaf(a.y, sc4.y, sh4.y), 0.f);
                b.x = fmaxf(fmaf(b.x, sc4.z, sh4.z), 0.f);
                b.y = fmaxf(fmaf(b.y, sc4.w, sh4.w), 0.f);
            }
            acc.x += wv[u] * a.x;
            acc.y += wv[u] * a.y;
            acc.z += wv[u] * b.x;
            acc.w += wv[u] * b.y;
        }
    }

    acc.x += __shfl_xor(acc.x, 16);
    acc.y += __shfl_xor(acc.y, 16);
    acc.z += __shfl_xor(acc.z, 16);
    acc.w += __shfl_xor(acc.w, 16);
    acc.x += __shfl_xor(acc.x, 32);
    acc.y += __shfl_xor(acc.y, 32);
    acc.z += __shfl_xor(acc.z, 32);
    acc.w += __shfl_xor(acc.w, 32);
    if (slot == 0) {
        uint2 o;
        o.x = packbf2(acc.x, acc.y);
        o.y = packbf2(acc.z, acc.w);
        *(uint2*)(outb + (size_t)node * 32 + li * 2) = o;
    }
}

// ---------------- bf16 MFMA GEMM: 128 rows/block, LDS-staged epilogue (R10) ----------

#define GTILE 128

__global__ __launch_bounds__(256) void mfma_gemm(const unsigned short* __restrict__ A,
                                                 const unsigned short* __restrict__ Wt,
                                                 const float* __restrict__ bias,
                                                 unsigned short* __restrict__ out,
                                                 float* __restrict__ stats_out,
                                                 const float* __restrict__ stats_in,
                                                 const float* __restrict__ gamma,
                                                 const float* __restrict__ beta,
                                                 int n, int transform) {
    __shared__ float sc[64], sh[64];
    __shared__ unsigned short cstage[GTILE * 64];
    __shared__ float rsum[64 * 17];
    __shared__ float rsq[64 * 17];

    const int t = threadIdx.x;
    if (transform && t < 64) {
        float inv_n = 1.0f / (float)n;
        float mean = stats_in[t] * inv_n;
        float var = stats_in[64 + t] * inv_n - mean * mean;
        float s = gamma[t] * rsqrtf(var + 1e-5f);
        sc[t] = s;
        sh[t] = beta[t] - mean * s;
    }
    __syncthreads();

    const int wid = t >> 6;
    const int lane = t & 63;
    const int m = lane & 15;
    const int q = lane >> 4;
    const int rowbase = blockIdx.x * GTILE + wid * 32;

    B16x8 bf[4][2];
#pragma unroll
    for (int tc = 0; tc < 4; ++tc)
#pragma unroll
        for (int kc = 0; kc < 2; ++kc)
            bf[tc][kc].u = *(const uint4*)(Wt + (size_t)(tc * 16 + m) * 64 + kc * 32 + q * 8);

    B16x8 af[2][2];
#pragma unroll
    for (int tr = 0; tr < 2; ++tr) {
        int gr = rowbase + tr * 16 + m;
#pragma unroll
        for (int kc = 0; kc < 2; ++kc) {
            if (gr < n)
                af[tr][kc].u = *(const uint4*)(A + (size_t)gr * 64 + kc * 32 + q * 8);
            else
                af[tr][kc].u = make_uint4(0, 0, 0, 0);
        }
    }

    if (transform) {
        int k0base = q * 8;
#pragma unroll
        for (int tr = 0; tr < 2; ++tr)
#pragma unroll
            for (int kc = 0; kc < 2; ++kc) {
                int k0 = kc * 32 + k0base;
                float4 s0 = *(const float4*)(sc + k0);
                float4 s1 = *(const float4*)(sc + k0 + 4);
                float4 h0 = *(const float4*)(sh + k0);
                float4 h1 = *(const float4*)(sh + k0 + 4);
                uint4 uu = af[tr][kc].u;
                float2 p0 = unpkbf2(uu.x), p1 = unpkbf2(uu.y);
                float2 p2 = unpkbf2(uu.z), p3 = unpkbf2(uu.w);
                p0.x = fmaxf(fmaf(p0.x, s0.x, h0.x), 0.f);
                p0.y = fmaxf(fmaf(p0.y, s0.y, h0.y), 0.f);
                p1.x = fmaxf(fmaf(p1.x, s0.z, h0.z), 0.f);
                p1.y = fmaxf(fmaf(p1.y, s0.w, h0.w), 0.f);
                p2.x = fmaxf(fmaf(p2.x, s1.x, h1.x), 0.f);
                p2.y = fmaxf(fmaf(p2.y, s1.y, h1.y), 0.f);
                p3.x = fmaxf(fmaf(p3.x, s1.z, h1.z), 0.f);
                p3.y = fmaxf(fmaf(p3.y, s1.w, h1.w), 0.f);
                uu.x = packbf2(p0.x, p0.y);
                uu.y = packbf2(p1.x, p1.y);
                uu.z = packbf2(p2.x, p2.y);
                uu.w = packbf2(p3.x, p3.y);
                af[tr][kc].u = uu;
            }
    }

    f32x4 acc[2][4];
#pragma unroll
    for (int tr = 0; tr < 2; ++tr)
#pragma unroll
        for (int tc = 0; tc < 4; ++tc) {
            acc[tr][tc] = (f32x4){0.f, 0.f, 0.f, 0.f};
            acc[tr][tc] = __builtin_amdgcn_mfma_f32_16x16x32_bf16(af[tr][0].s, bf[tc][0].s,
                                                                  acc[tr][tc], 0, 0, 0);
            acc[tr][tc] = __builtin_amdgcn_mfma_f32_16x16x32_bf16(af[tr][1].s, bf[tc][1].s,
                                                                  acc[tr][tc], 0, 0, 0);
        }

    float bc[4];
#pragma unroll
    for (int tc = 0; tc < 4; ++tc) bc[tc] = bias[tc * 16 + m];

    float psum[4] = {0, 0, 0, 0}, psq[4] = {0, 0, 0, 0};
#pragma unroll
    for (int tr = 0; tr < 2; ++tr)
#pragma unroll
        for (int reg = 0; reg < 4; ++reg) {
            int rl = wid * 32 + tr * 16 + q * 4 + reg;
            int gr = blockIdx.x * GTILE + rl;
            int sw = ((rl >> 2) & 3) << 4;
            bool ok = gr < n;
#pragma unroll
            for (int tc = 0; tc < 4; ++tc) {
                float val = acc[tr][tc][reg] + bc[tc];
                int col = tc * 16 + m;
                cstage[rl * 64 + (col ^ sw)] = (unsigned short)bf16rn(ok ? val : 0.f);
                if (ok) {
                    psum[tc] += val;
                    psq[tc] += val * val;
                }
            }
        }

    int contrib = wid * 4 + q;
#pragma unroll
    for (int tc = 0; tc < 4; ++tc) {
        int c = tc * 16 + m;
        rsum[c * 17 + contrib] = psum[tc];
        rsq[c * 17 + contrib] = psq[tc];
    }
    __syncthreads();

#pragma unroll
    for (int rep = 0; rep < 4; ++rep) {
        int idx = rep * 256 + t;
        int rl = idx >> 3;
        int k = idx & 7;
        int gr = blockIdx.x * GTILE + rl;
        if (gr < n) {
            int klds = k ^ (((rl >> 2) & 3) << 1);
            uint4 v = *(const uint4*)(cstage + rl * 64 + klds * 8);
            *(uint4*)(out + (size_t)gr * 64 + k * 8) = v;
        }
    }

    if (t < 64) {
        float s = 0.f, qq = 0.f;
#pragma unroll
        for (int i = 0; i < 16; ++i) {
            s += rsum[t * 17 + i];
            qq += rsq[t * 17 + i];
        }
        atomicAdd(&stats_out[t], s);
        atomicAdd(&stats_out[64 + t], qq);
    }
}

// ---------------- standalone pool+score (final layer only) ----------------

__global__ __launch_bounds__(256) void pool_score_kernel(const unsigned* __restrict__ hb,
                                                         const int* __restrict__ start,
                                                         const float* __restrict__ pW,
                                                         const float* __restrict__ pb,
                                                         float* __restrict__ score,
                                                         const float* __restrict__ stats,
                                                         const float* __restrict__ gamma,
                                                         const float* __restrict__ beta,
                                                         int n, int mode) {
    __shared__ float red[16][68];
    __shared__ float sc[64], sh[64], pl[64];
    const int t = threadIdx.x;
    const int g = blockIdx.x;
    if (mode && t < 64) {
        float inv_n = 1.0f / (float)n;
        float mean = stats[t] * inv_n;
        float var = stats[64 + t] * inv_n - mean * mean;
        float s = gamma[t] * rsqrtf(var + 1e-5f);
        sc[t] = s;
        sh[t] = beta[t] - mean * s;
    }
    __syncthreads();

    const int r16 = t >> 4;
    const int qq = t & 15;
    const int k0 = qq << 2;
    int i0 = start[g], i1 = start[g + 1];
    float4 ps = make_float4(0.f, 0.f, 0.f, 0.f);
    for (int i = i0 + r16; i < i1; i += 16) {
        uint2 u = *(const uint2*)(hb + (size_t)i * 32 + qq * 2);
        float2 a = unpkbf2(u.x);
        float2 b = unpkbf2(u.y);
        if (mode) {
            a.x = fmaxf(fmaf(a.x, sc[k0 + 0], sh[k0 + 0]), 0.f);
            a.y = fmaxf(fmaf(a.y, sc[k0 + 1], sh[k0 + 1]), 0.f);
            b.x = fmaxf(fmaf(b.x, sc[k0 + 2], sh[k0 + 2]), 0.f);
            b.y = fmaxf(fmaf(b.y, sc[k0 + 3], sh[k0 + 3]), 0.f);
        }
        ps.x += a.x; ps.y += a.y; ps.z += b.x; ps.w += b.y;
    }
    red[r16][k0 + 0] = ps.x;
    red[r16][k0 + 1] = ps.y;
    red[r16][k0 + 2] = ps.z;
    red[r16][k0 + 3] = ps.w;
    __syncthreads();
    if (t < 64) {
        float s = 0.f;
#pragma unroll
        for (int r = 0; r < 16; ++r) s += red[r][t];
        pl[t] = s;
    }
    __syncthreads();
    if (t < 16) {
        float s = pb[t];
#pragma unroll 8
        for (int d = 0; d < 64; ++d) s += pl[d] * pW[d * 16 + t];
        score[g * 16 + t] = mode ? (score[g * 16 + t] + s) : s;
    }
}

// ---------------- host ----------------

extern "C" void kernel_launch(void* const* d_in, const int* in_sizes, int n_in,
                              void* d_out, int out_size, void* d_ws, size_t ws_size,
                              hipStream_t stream) {
    const float* x = (const float*)d_in[0];
    const float* w = (const float*)d_in[1];
    const int* src = (const int*)d_in[2];
    const int* dst = (const int*)d_in[3];
    const int* gid = (const int*)d_in[4];
    const float* eps = (const float*)d_in[5];
    const float* W1 = (const float*)d_in[6];
    const float* b1 = (const float*)d_in[7];
    const float* bng = (const float*)d_in[8];
    const float* bnb = (const float*)d_in[9];
    const float* W2 = (const float*)d_in[10];
    const float* b2 = (const float*)d_in[11];
    const float* og = (const float*)d_in[12];
    const float* ob = (const float*)d_in[13];
    const float* pW = (const float*)d_in[14];
    const float* pb = (const float*)d_in[15];
    float* out = (float*)d_out;

    const int N = N_NODES, E = N_EDGES, G = N_GRAPHS;

    unsigned* base = (unsigned*)d_ws;
    unsigned* xb = base;                       // N*32
    unsigned* HA = xb + (size_t)N * 32;        // N*32
    unsigned* HB = HA + (size_t)N * 32;        // N*32
    float* stats = (float*)(HB + (size_t)N * 32);  // 1024 f32 (zeroed)
    int* cursor = (int*)(stats + 1024);        // NB2 (zeroed), padded to 392
    int* start = cursor + NB2 + 1;             // 132 ints
    int2* row_se = (int2*)(start + 132);       // N+8 int2 (8B-aligned by construction)
    unsigned short* Wt = (unsigned short*)(row_se + N + 8);  // 8*4096 bf16
    int2* tmp = (int2*)(Wt + 8 * 4096);        // NB2*BCAP int2 = 12.8 MB
    unsigned* pack = (unsigned*)(tmp + (size_t)NB2 * BCAP);  // NB2*BCAP uint = 6.4 MB

    hipMemsetAsync(stats, 0, (size_t)(1024 + NB2 + 1) * sizeof(float), stream);

    hipLaunchKernelGGL(setup_partition_kernel, dim3(PART_BLOCKS), dim3(256), 0, stream, dst, src,
                       w, cursor, tmp, E, x, xb, W1, W2, Wt, gid, start, N, G);
    hipLaunchKernelGGL(node_sort_kernel, dim3(NB2), dim3(256), 0, stream, tmp, cursor, row_se,
                       pack, N);

    const int agg_blocks = (N + 3) / 4;  // 12500
    const int gemm_blocks = (N + GTILE - 1) / GTILE;
    unsigned* cur = xb;
    unsigned* P = HA;
    unsigned* Q = HB;
    for (int l = 0; l < 4; ++l) {
        const float* tr_stats = (l == 0) ? nullptr : stats + (l - 1) * 256 + 128;
        const float* tr_g = (l == 0) ? nullptr : og + (l - 1) * 64;
        const float* tr_b = (l == 0) ? nullptr : ob + (l - 1) * 64;
        // agg of cur (with prev outer BN) -> P; extra 128 blocks pool cur -> score[pW_l]
        hipLaunchKernelGGL(agg_kernel, dim3(agg_blocks + G), dim3(256), 0, stream, cur, pack,
                           row_se, eps, l, P, N, tr_stats, tr_g, tr_b, l == 0 ? 0 : 1,
                           agg_blocks, start, pW + (size_t)l * 1024, pb + l * 16, out);
        hipLaunchKernelGGL(mfma_gemm, dim3(gemm_blocks), dim3(256), 0, stream,
                           (const unsigned short*)P, Wt + (size_t)(l * 2) * 4096, b1 + l * 64,
                           (unsigned short*)Q, stats + l * 256, (const float*)nullptr,
                           (const float*)nullptr, (const float*)nullptr, N, 0);
        hipLaunchKernelGGL(mfma_gemm, dim3(gemm_blocks), dim3(256), 0, stream,
                           (const unsigned short*)Q, Wt + (size_t)(l * 2 + 1) * 4096, b2 + l * 64,
                           (unsigned short*)P, stats + l * 256 + 128, stats + l * 256,
                           bng + l * 64, bnb + l * 64, N, 1);
        cur = P;
        unsigned* t2 = P;
        P = Q;
        Q = t2;
    }
    // final pool of h_3 with layer-3 outer BN -> score[pW_4]
    hipLaunchKernelGGL(pool_score_kernel, dim3(G), dim3(256), 0, stream, cur, start,
                       pW + 4 * 1024, pb + 4 * 16, out, stats + 3 * 256 + 128, og + 3 * 64,
                       ob + 3 * 64, N, 1);
}